// Round 1
// baseline (237.839 us; speedup 1.0000x reference)
//
#include <hip/hip_runtime.h>
#include <stdint.h>

#define N_Q 16384
#define M_P 1024
#define D_K 1024

typedef __attribute__((ext_vector_type(8))) __bf16 bf16x8;
typedef __attribute__((ext_vector_type(4))) float floatx4;

#define AS1 __attribute__((address_space(1)))
#define AS3 __attribute__((address_space(3)))

__device__ __forceinline__ unsigned short f2bf(float f) {
    unsigned int u = __float_as_uint(f);
    u += 0x7fffu + ((u >> 16) & 1u);   // round-to-nearest-even
    return (unsigned short)(u >> 16);
}
__device__ __forceinline__ float bf2f(unsigned short h) {
    return __uint_as_float(((unsigned int)h) << 16);
}

// ---------------------------------------------------------------------------
// Split fp32 -> bf16 hi/lo (query).  One float4 per thread.
// ---------------------------------------------------------------------------
__global__ __launch_bounds__(256) void convert_split_kernel(
    const float* __restrict__ src, unsigned short* __restrict__ hi,
    unsigned short* __restrict__ lo, int n4) {
    int idx = blockIdx.x * 256 + threadIdx.x;
    if (idx >= n4) return;
    float4 v = ((const float4*)src)[idx];
    float a0 = v.x, a1 = v.y, a2 = v.z, a3 = v.w;
    ushort4 h, l;
    h.x = f2bf(a0); l.x = f2bf(a0 - bf2f(h.x));
    h.y = f2bf(a1); l.y = f2bf(a1 - bf2f(h.y));
    h.z = f2bf(a2); l.z = f2bf(a2 - bf2f(h.z));
    h.w = f2bf(a3); l.w = f2bf(a3 - bf2f(h.w));
    ((ushort4*)hi)[idx] = h;
    ((ushort4*)lo)[idx] = l;
}

// ---------------------------------------------------------------------------
// Proto: split fp32 -> bf16 hi/lo AND compute p2[m] = ||proto_m||^2.
// One block (256 threads) per proto row; D=1024 -> one float4 per thread.
// ---------------------------------------------------------------------------
__global__ __launch_bounds__(256) void convert_proto_kernel(
    const float* __restrict__ proto, unsigned short* __restrict__ hi,
    unsigned short* __restrict__ lo, float* __restrict__ p2) {
    int m = blockIdx.x;
    int t = threadIdx.x;
    size_t base4 = (size_t)m * (D_K / 4) + t;
    float4 v = ((const float4*)proto)[base4];
    float a0 = v.x, a1 = v.y, a2 = v.z, a3 = v.w;
    ushort4 h, l;
    h.x = f2bf(a0); l.x = f2bf(a0 - bf2f(h.x));
    h.y = f2bf(a1); l.y = f2bf(a1 - bf2f(h.y));
    h.z = f2bf(a2); l.z = f2bf(a2 - bf2f(h.z));
    h.w = f2bf(a3); l.w = f2bf(a3 - bf2f(h.w));
    ((ushort4*)hi)[base4] = h;
    ((ushort4*)lo)[base4] = l;

    float sq = a0 * a0 + a1 * a1 + a2 * a2 + a3 * a3;
#pragma unroll
    for (int off = 1; off < 64; off <<= 1) sq += __shfl_xor(sq, off);
    __shared__ float sred[4];
    if ((t & 63) == 0) sred[t >> 6] = sq;
    __syncthreads();
    if (t == 0) p2[m] = sred[0] + sred[1] + sred[2] + sred[3];
}

// ---------------------------------------------------------------------------
// GEMM: logits[n,m] = 2 * sum_d q[n,d]*p[m,d] - p2[m], via bf16 hi/lo split:
//   qp = qh.ph + qh.pl + ql.ph   (ql.pl dropped, ~1e-4 error)
// 128x128 tile, BK=32, 4 waves -> 2x2 of 64x64, mfma_f32_16x16x32_bf16.
// global_load_lds width=16 staging: wave w stages tile w of {Ah,Al,Bh,Bl}.
// ---------------------------------------------------------------------------
__global__ __launch_bounds__(256, 3) void gemm_logits_kernel(
    const unsigned short* __restrict__ qh, const unsigned short* __restrict__ ql,
    const unsigned short* __restrict__ ph, const unsigned short* __restrict__ pl,
    const float* __restrict__ p2, float* __restrict__ out) {
    __shared__ unsigned short lds[4 * 128 * 32];  // Ah | Al | Bh | Bl, 32 KB

    const int tid = threadIdx.x;
    const int wave = tid >> 6;
    const int lane = tid & 63;
    const int nt = blockIdx.x & 127;   // query tile (consecutive blocks share mt)
    const int mt = blockIdx.x >> 7;    // proto tile
    const int row0 = nt * 128;
    const int col0 = mt * 128;

    unsigned short* sAh = lds;
    unsigned short* sAl = lds + 4096;
    unsigned short* sBh = lds + 8192;
    unsigned short* sBl = lds + 12288;

    // Staging assignment: one wave per tile.
    const unsigned short* gsrc;
    unsigned short* ldst;
    int grow0;
    if (wave == 0)      { gsrc = qh; grow0 = row0; ldst = sAh; }
    else if (wave == 1) { gsrc = ql; grow0 = row0; ldst = sAl; }
    else if (wave == 2) { gsrc = ph; grow0 = col0; ldst = sBh; }
    else                { gsrc = pl; grow0 = col0; ldst = sBl; }

    // Per-lane staging source: chunk c = i*64+lane; row=i*16+(lane>>2), cio=lane&3
    const int rl = lane >> 2;
    const int cio = lane & 3;
    const unsigned short* gbase = gsrc + (size_t)(grow0 + rl) * D_K + cio * 8;

    floatx4 zero = {0.0f, 0.0f, 0.0f, 0.0f};
    floatx4 acc[4][4];
#pragma unroll
    for (int i = 0; i < 4; ++i)
#pragma unroll
        for (int j = 0; j < 4; ++j) acc[i][j] = zero;

    const int wrow = (wave & 1) * 64;
    const int wcol = (wave >> 1) * 64;
    const int rsel = lane & 15;
    const int kq = lane >> 4;

    for (int kt = 0; kt < D_K / 32; ++kt) {
        // ---- stage global -> LDS (async, 16B/lane) ----
#pragma unroll
        for (int i = 0; i < 8; ++i) {
            const unsigned short* gp = gbase + (size_t)i * 16 * D_K + kt * 32;
            __builtin_amdgcn_global_load_lds(
                (const AS1 unsigned int*)(const void*)gp,
                (AS3 unsigned int*)(void*)(ldst + i * 512), 16, 0, 0);
        }
        __syncthreads();

        // ---- fragment loads (ds_read_b128) ----
        bf16x8 ah[4], al[4], bh[4], bl[4];
#pragma unroll
        for (int i = 0; i < 4; ++i) {
            const int aoff = (wrow + i * 16 + rsel) * 32 + kq * 8;
            ah[i] = *(const bf16x8*)(sAh + aoff);
            al[i] = *(const bf16x8*)(sAl + aoff);
            const int boff = (wcol + i * 16 + rsel) * 32 + kq * 8;
            bh[i] = *(const bf16x8*)(sBh + boff);
            bl[i] = *(const bf16x8*)(sBl + boff);
        }

        // ---- 3-term MFMA accumulate ----
#pragma unroll
        for (int i = 0; i < 4; ++i)
#pragma unroll
            for (int j = 0; j < 4; ++j) {
                acc[i][j] = __builtin_amdgcn_mfma_f32_16x16x32_bf16(ah[i], bh[j], acc[i][j], 0, 0, 0);
                acc[i][j] = __builtin_amdgcn_mfma_f32_16x16x32_bf16(ah[i], bl[j], acc[i][j], 0, 0, 0);
                acc[i][j] = __builtin_amdgcn_mfma_f32_16x16x32_bf16(al[i], bh[j], acc[i][j], 0, 0, 0);
            }
        __syncthreads();
    }

    // ---- epilogue: logits = 2*qp - p2[col] ----
    // C layout (verified m89/m91): col = lane&15, row = (lane>>4)*4 + reg
#pragma unroll
    for (int j = 0; j < 4; ++j) {
        const int gc = col0 + wcol + j * 16 + rsel;
        const float p2v = p2[gc];
#pragma unroll
        for (int i = 0; i < 4; ++i) {
            const int gr = row0 + wrow + i * 16 + kq * 4;
#pragma unroll
            for (int r = 0; r < 4; ++r) {
                out[(size_t)(gr + r) * M_P + gc] = 2.0f * acc[i][j][r] - p2v;
            }
        }
    }
}

// ---------------------------------------------------------------------------
// Fallback (tiny workspace): naive fp32 logits, p2 folded in per-thread.
// One block per query row; thread t handles m = t + 256*j.
// ---------------------------------------------------------------------------
__global__ __launch_bounds__(256) void naive_logits_kernel(
    const float* __restrict__ query, const float* __restrict__ proto,
    float* __restrict__ out) {
    __shared__ float qs[D_K];
    int n = blockIdx.x;
    int t = threadIdx.x;
    ((float4*)qs)[t] = ((const float4*)(query + (size_t)n * D_K))[t];
    __syncthreads();
    float acc[4] = {0.f, 0.f, 0.f, 0.f};
    float pp[4] = {0.f, 0.f, 0.f, 0.f};
    for (int d = 0; d < D_K; d += 4) {
        float4 qv = *(const float4*)(qs + d);
#pragma unroll
        for (int j = 0; j < 4; ++j) {
            const float4 pv = *(const float4*)(proto + (size_t)(t + 256 * j) * D_K + d);
            acc[j] += qv.x * pv.x + qv.y * pv.y + qv.z * pv.z + qv.w * pv.w;
            pp[j] += pv.x * pv.x + pv.y * pv.y + pv.z * pv.z + pv.w * pv.w;
        }
    }
#pragma unroll
    for (int j = 0; j < 4; ++j)
        out[(size_t)n * M_P + t + 256 * j] = 2.0f * acc[j] - pp[j];
}

// ---------------------------------------------------------------------------
// In-place row softmax over M=1024 (one block/row, one float4/thread).
// ---------------------------------------------------------------------------
__global__ __launch_bounds__(256) void softmax_kernel(float* __restrict__ out) {
    int n = blockIdx.x;
    int t = threadIdx.x;
    float4* row = (float4*)(out + (size_t)n * M_P);
    float4 v = row[t];
    float mx = fmaxf(fmaxf(v.x, v.y), fmaxf(v.z, v.w));
#pragma unroll
    for (int off = 1; off < 64; off <<= 1) mx = fmaxf(mx, __shfl_xor(mx, off));
    __shared__ float smax[4];
    __shared__ float ssum[4];
    int wave = t >> 6, lane = t & 63;
    if (lane == 0) smax[wave] = mx;
    __syncthreads();
    mx = fmaxf(fmaxf(smax[0], smax[1]), fmaxf(smax[2], smax[3]));
    float e0 = __expf(v.x - mx), e1 = __expf(v.y - mx);
    float e2 = __expf(v.z - mx), e3 = __expf(v.w - mx);
    float s = e0 + e1 + e2 + e3;
#pragma unroll
    for (int off = 1; off < 64; off <<= 1) s += __shfl_xor(s, off);
    if (lane == 0) ssum[wave] = s;
    __syncthreads();
    float inv = 1.0f / (ssum[0] + ssum[1] + ssum[2] + ssum[3]);
    float4 o;
    o.x = e0 * inv; o.y = e1 * inv; o.z = e2 * inv; o.w = e3 * inv;
    row[t] = o;
}

extern "C" void kernel_launch(void* const* d_in, const int* in_sizes, int n_in,
                              void* d_out, int out_size, void* d_ws, size_t ws_size,
                              hipStream_t stream) {
    const float* query = (const float*)d_in[0];
    const float* proto = (const float*)d_in[1];
    float* out = (float*)d_out;

    const size_t qElems = (size_t)N_Q * D_K;   // 16M
    const size_t pElems = (size_t)M_P * D_K;   // 1M
    const size_t needed = qElems * 2 * 2 + pElems * 2 * 2 + M_P * 4;  // ~68 MiB

    if (ws_size >= needed) {
        unsigned short* qh = (unsigned short*)d_ws;
        unsigned short* ql = qh + qElems;
        unsigned short* ph = ql + qElems;
        unsigned short* pl = ph + pElems;
        float* p2 = (float*)(pl + pElems);

        convert_split_kernel<<<(int)(qElems / 4 / 256), 256, 0, stream>>>(
            query, qh, ql, (int)(qElems / 4));
        convert_proto_kernel<<<M_P, 256, 0, stream>>>(proto, ph, pl, p2);
        gemm_logits_kernel<<<(N_Q / 128) * (M_P / 128), 256, 0, stream>>>(
            qh, ql, ph, pl, p2, out);
    } else {
        naive_logits_kernel<<<N_Q, 256, 0, stream>>>(query, proto, out);
    }
    softmax_kernel<<<N_Q, 256, 0, stream>>>(out);
}